// Round 9
// baseline (359.998 us; speedup 1.0000x reference)
//
#include <hip/hip_runtime.h>
#include <hip/hip_fp16.h>

// GCN 3-layer encoder. R9 = R8 + channel-split aggregation (two serialized
// passes per layer, 64 channels each -> 12.8MB working set per pass, better
// per-XCD L2 hit) + CSR build with CHUNK 4096 (391 blocks) and int4 edge reads.
// - CSR build: 2-level counting sort (no global atomics).
// - GEMM: fp16 MFMA 16x16x32, swapped operands, fp32 acc, epilogue *dinv -> fp16.
// - Agg: out[i] = di*(sum_e h_pre[src] + h_pre[i]) + b; 8-lane x 16B row gather.

#define K_DIM 128
#define CHUNK 4096
#define NBMAX 1024
#define BSH 8          // bucket shift: 256 nodes per bucket
#define BMASK 255

typedef _Float16 f16x8 __attribute__((ext_vector_type(8)));
typedef float f32x4 __attribute__((ext_vector_type(4)));

// ---------------- preprocessing: counting-sort CSR build ----------------

__global__ __launch_bounds__(256) void hist_pass(const int* __restrict__ col, int E,
                                                 int NB, int B1, int* __restrict__ histG) {
    __shared__ int h[NBMAX];
    const int tid = threadIdx.x;
    for (int i = tid; i < NB; i += 256) h[i] = 0;
    __syncthreads();
    const int base = blockIdx.x * CHUNK;
    const int bend = min(base + CHUNK, E);
    for (int idx = base + tid * 4; idx < bend; idx += 1024) {
        if (idx + 4 <= bend) {
            int4 c4 = *(const int4*)&col[idx];
            atomicAdd(&h[c4.x >> BSH], 1);
            atomicAdd(&h[c4.y >> BSH], 1);
            atomicAdd(&h[c4.z >> BSH], 1);
            atomicAdd(&h[c4.w >> BSH], 1);
        } else {
            for (int j = 0; j < 4 && idx + j < bend; ++j)
                atomicAdd(&h[col[idx + j] >> BSH], 1);
        }
    }
    __syncthreads();
    for (int i = tid; i < NB; i += 256) histG[(size_t)i * B1 + blockIdx.x] = h[i];
}

__global__ __launch_bounds__(256) void scan_blocks(int* __restrict__ data, int n,
                                                   int* __restrict__ bsum) {
    __shared__ int sh[256];
    const int tid = threadIdx.x;
    const int base = blockIdx.x * 1024;
    int v[4];
    int sum = 0;
#pragma unroll
    for (int j = 0; j < 4; ++j) {
        int i = base + tid * 4 + j;
        v[j] = (i < n) ? data[i] : 0;
        sum += v[j];
    }
    sh[tid] = sum;
    __syncthreads();
#pragma unroll
    for (int off = 1; off < 256; off <<= 1) {
        int t = (tid >= off) ? sh[tid - off] : 0;
        __syncthreads();
        sh[tid] += t;
        __syncthreads();
    }
    int run = (tid > 0) ? sh[tid - 1] : 0;
#pragma unroll
    for (int j = 0; j < 4; ++j) {
        int i = base + tid * 4 + j;
        if (i < n) data[i] = run;
        run += v[j];
    }
    if (tid == 255) bsum[blockIdx.x] = sh[255];
}

__global__ __launch_bounds__(256) void scan_single(int* __restrict__ data, int n) {
    __shared__ int sh[256];
    const int tid = threadIdx.x;
    int v[4];
    int sum = 0;
#pragma unroll
    for (int j = 0; j < 4; ++j) {
        int i = tid * 4 + j;
        v[j] = (i < n) ? data[i] : 0;
        sum += v[j];
    }
    sh[tid] = sum;
    __syncthreads();
#pragma unroll
    for (int off = 1; off < 256; off <<= 1) {
        int t = (tid >= off) ? sh[tid - off] : 0;
        __syncthreads();
        sh[tid] += t;
        __syncthreads();
    }
    int run = (tid > 0) ? sh[tid - 1] : 0;
#pragma unroll
    for (int j = 0; j < 4; ++j) {
        int i = tid * 4 + j;
        if (i < n) data[i] = run;
        run += v[j];
    }
}

// scatter with bsum folded: global cursor = histG[idx] + bsum[idx>>10]
__global__ __launch_bounds__(256) void scatter_pass(const int* __restrict__ row,
                                                    const int* __restrict__ col, int E,
                                                    int NB, int B1,
                                                    const int* __restrict__ histG,
                                                    const int* __restrict__ bsum,
                                                    int* __restrict__ ebuf) {
    __shared__ int cur[NBMAX];
    const int tid = threadIdx.x;
    for (int i = tid; i < NB; i += 256) {
        const size_t idx = (size_t)i * B1 + blockIdx.x;
        cur[i] = histG[idx] + bsum[idx >> 10];
    }
    __syncthreads();
    const int base = blockIdx.x * CHUNK;
    const int bend = min(base + CHUNK, E);
    for (int idx = base + tid * 4; idx < bend; idx += 1024) {
        if (idx + 4 <= bend) {
            int4 d4 = *(const int4*)&col[idx];
            int4 s4 = *(const int4*)&row[idx];
            int p0 = atomicAdd(&cur[d4.x >> BSH], 1);
            ebuf[p0] = (s4.x << BSH) | (d4.x & BMASK);
            int p1 = atomicAdd(&cur[d4.y >> BSH], 1);
            ebuf[p1] = (s4.y << BSH) | (d4.y & BMASK);
            int p2 = atomicAdd(&cur[d4.z >> BSH], 1);
            ebuf[p2] = (s4.z << BSH) | (d4.z & BMASK);
            int p3 = atomicAdd(&cur[d4.w >> BSH], 1);
            ebuf[p3] = (s4.w << BSH) | (d4.w & BMASK);
        } else {
            for (int j = 0; j < 4 && idx + j < bend; ++j) {
                int d = col[idx + j];
                int s = row[idx + j];
                int pos = atomicAdd(&cur[d >> BSH], 1);
                ebuf[pos] = (s << BSH) | (d & BMASK);
            }
        }
    }
}

__global__ __launch_bounds__(256) void build_csr(const int* __restrict__ ebuf,
                                                 const int* __restrict__ histG,
                                                 const int* __restrict__ bsum,
                                                 int NB, int B1, int N, int E,
                                                 int* __restrict__ offs,
                                                 float* __restrict__ dinv,
                                                 int* __restrict__ csr) {
    __shared__ int cnt[256];
    __shared__ int scn[256];
    __shared__ int curL[256];
    const int tid = threadIdx.x;
    const int b = blockIdx.x;
    const size_t iS = (size_t)b * B1;
    const int S = histG[iS] + bsum[iS >> 10];
    int T = E;
    if (b + 1 < NB) {
        const size_t iT = (size_t)(b + 1) * B1;
        T = histG[iT] + bsum[iT >> 10];
    }

    cnt[tid] = 0;
    __syncthreads();
    for (int i = S + tid; i < T; i += 256) atomicAdd(&cnt[ebuf[i] & BMASK], 1);
    __syncthreads();
    scn[tid] = cnt[tid];
    __syncthreads();
#pragma unroll
    for (int off = 1; off < 256; off <<= 1) {
        int t = (tid >= off) ? scn[tid - off] : 0;
        __syncthreads();
        scn[tid] += t;
        __syncthreads();
    }
    {
        int exc = (tid > 0) ? scn[tid - 1] : 0;
        int node = b * 256 + tid;
        if (node < N) {
            offs[node] = S + exc;
            dinv[node] = rsqrtf((float)(cnt[tid] + 1));
        }
        curL[tid] = S + exc;
    }
    if (b == 0 && tid == 0) offs[N] = E;
    __syncthreads();
    for (int i = S + tid; i < T; i += 256) {
        int p = ebuf[i];
        int pos = atomicAdd(&curL[p & BMASK], 1);
        csr[pos] = p >> BSH;
    }
}

// W[k][nc] fp32 -> wT[n*128 + k] fp16 (transposed), all three weights
__global__ void prep_wT(const float* __restrict__ W1, const float* __restrict__ W2,
                        const float* __restrict__ W3, __half* __restrict__ wT1,
                        __half* __restrict__ wT2, __half* __restrict__ wT3) {
    int tid = blockIdx.x * 256 + threadIdx.x;
    if (tid < 16384) {
        int n = tid >> 7, k = tid & 127;
        wT1[tid] = __float2half(W1[k * 128 + n]);
    } else if (tid < 32768) {
        int t = tid - 16384;
        int n = t >> 7, k = t & 127;
        wT2[t] = __float2half(W2[k * 128 + n]);
    } else if (tid < 40960) {
        int t = tid - 32768;
        int n = t >> 7, k = t & 127;  // n in [0,64)
        wT3[t] = __float2half(W3[k * 64 + n]);
    }
}

// ------------- layer-1 GEMM with fused fp32->fp16 cast -------------

__global__ __launch_bounds__(256) void gemm_x(const float* __restrict__ X,    // [M][128] fp32
                                              const __half* __restrict__ wT,  // [128][128]
                                              const float* __restrict__ dinv,
                                              __half* __restrict__ out, int M) {
    const int tid = threadIdx.x;
    const int wave = tid >> 6;
    const int l = tid & 63;
    const int lm = l & 15;
    const int kg = l >> 4;
    const int row0 = blockIdx.x * 128 + wave * 32;

    f32x4 acc[2][8];
#pragma unroll
    for (int mt = 0; mt < 2; ++mt)
#pragma unroll
        for (int nt = 0; nt < 8; ++nt) acc[mt][nt] = {0.f, 0.f, 0.f, 0.f};

    const int m0 = row0 + lm;
    const int m1 = row0 + 16 + lm;
    const int mc0 = min(m0, M - 1);
    const int mc1 = min(m1, M - 1);

#pragma unroll
    for (int ks = 0; ks < 4; ++ks) {
        const int k0 = ks * 32 + kg * 8;
        float4 u0 = *(const float4*)&X[(size_t)mc0 * 128 + k0];
        float4 u1 = *(const float4*)&X[(size_t)mc0 * 128 + k0 + 4];
        float4 u2 = *(const float4*)&X[(size_t)mc1 * 128 + k0];
        float4 u3 = *(const float4*)&X[(size_t)mc1 * 128 + k0 + 4];
        f16x8 b0 = {(_Float16)u0.x, (_Float16)u0.y, (_Float16)u0.z, (_Float16)u0.w,
                    (_Float16)u1.x, (_Float16)u1.y, (_Float16)u1.z, (_Float16)u1.w};
        f16x8 b1 = {(_Float16)u2.x, (_Float16)u2.y, (_Float16)u2.z, (_Float16)u2.w,
                    (_Float16)u3.x, (_Float16)u3.y, (_Float16)u3.z, (_Float16)u3.w};
#pragma unroll
        for (int nt = 0; nt < 8; ++nt) {
            f16x8 a = *(const f16x8*)&wT[(size_t)(nt * 16 + lm) * 128 + k0];
            acc[0][nt] = __builtin_amdgcn_mfma_f32_16x16x32_f16(a, b0, acc[0][nt], 0, 0, 0);
            acc[1][nt] = __builtin_amdgcn_mfma_f32_16x16x32_f16(a, b1, acc[1][nt], 0, 0, 0);
        }
    }

#pragma unroll
    for (int mt = 0; mt < 2; ++mt) {
        const int m = (mt == 0) ? m0 : m1;
        if (m < M) {
            const float dv = dinv[m];
#pragma unroll
            for (int nt = 0; nt < 8; ++nt) {
                float z0 = acc[mt][nt][0] * dv, z1 = acc[mt][nt][1] * dv;
                float z2 = acc[mt][nt][2] * dv, z3 = acc[mt][nt][3] * dv;
                __half2 o[2] = {__float22half2_rn(make_float2(z0, z1)),
                                __float22half2_rn(make_float2(z2, z3))};
                *(float2*)&out[(size_t)m * 128 + nt * 16 + kg * 4] = *(float2*)o;
            }
        }
    }
}

// ------------- fp16 GEMM (layers 2,3): out = (A @ W') * dinv, fp16 out -------------

template <int NCOLS>
__global__ __launch_bounds__(256) void gemm_f16(const __half* __restrict__ A,   // [M][128]
                                                const __half* __restrict__ wT,  // [NCOLS][128]
                                                const float* __restrict__ dinv,
                                                __half* __restrict__ out, int M) {
    constexpr int NT = NCOLS / 16;  // 8 or 4
    __shared__ __half sWT[NCOLS][136];  // pad +8 halves

    const int tid = threadIdx.x;
    for (int idx = tid; idx < NCOLS * 16; idx += 256) {
        int n = idx >> 4, kc = (idx & 15) * 8;
        *(float4*)&sWT[n][kc] = *(const float4*)&wT[n * 128 + kc];
    }
    __syncthreads();

    const int wave = tid >> 6;
    const int l = tid & 63;
    const int lm = l & 15;
    const int kg = l >> 4;
    const int row0 = blockIdx.x * 128 + wave * 32;

    f32x4 acc[2][NT];
#pragma unroll
    for (int mt = 0; mt < 2; ++mt)
#pragma unroll
        for (int nt = 0; nt < NT; ++nt) acc[mt][nt] = {0.f, 0.f, 0.f, 0.f};

    const int m0 = row0 + lm;
    const int m1 = row0 + 16 + lm;
    const int mc0 = min(m0, M - 1);
    const int mc1 = min(m1, M - 1);

#pragma unroll
    for (int ks = 0; ks < 4; ++ks) {
        const int k0 = ks * 32 + kg * 8;
        f16x8 b0 = *(const f16x8*)&A[(size_t)mc0 * 128 + k0];
        f16x8 b1 = *(const f16x8*)&A[(size_t)mc1 * 128 + k0];
#pragma unroll
        for (int nt = 0; nt < NT; ++nt) {
            f16x8 a = *(const f16x8*)&sWT[nt * 16 + lm][k0];
            acc[0][nt] = __builtin_amdgcn_mfma_f32_16x16x32_f16(a, b0, acc[0][nt], 0, 0, 0);
            acc[1][nt] = __builtin_amdgcn_mfma_f32_16x16x32_f16(a, b1, acc[1][nt], 0, 0, 0);
        }
    }

#pragma unroll
    for (int mt = 0; mt < 2; ++mt) {
        const int m = (mt == 0) ? m0 : m1;
        if (m < M) {
            const float dv = dinv[m];
#pragma unroll
            for (int nt = 0; nt < NT; ++nt) {
                float z0 = acc[mt][nt][0] * dv, z1 = acc[mt][nt][1] * dv;
                float z2 = acc[mt][nt][2] * dv, z3 = acc[mt][nt][3] * dv;
                __half2 o[2] = {__float22half2_rn(make_float2(z0, z1)),
                                __float22half2_rn(make_float2(z2, z3))};
                *(float2*)&out[(size_t)m * NCOLS + nt * 16 + kg * 4] = *(float2*)o;
            }
        }
    }
}

// ------- aggregation, channel-split: one pass covers 64 of 128 channels -------
// 8 lanes x 16B = 128B half-row per edge; 8 edge slots/wave; 2 gathers in flight.

template <bool RELU>
__global__ __launch_bounds__(256) void agg128h(const __half* __restrict__ h,  // [N][128]
                                               const float* __restrict__ dinv,
                                               const int* __restrict__ offs,
                                               const int* __restrict__ csr,
                                               const float* __restrict__ bias,
                                               __half* __restrict__ out, int N, int half) {
    const int wid = (blockIdx.x * 256 + threadIdx.x) >> 6;
    if (wid >= N) return;
    const int l = threadIdx.x & 63;
    const int q = l >> 3;           // edge slot 0..7
    const int cc = half * 8 + (l & 7);  // 16B chunk within full row (0..15)
    const int beg = offs[wid], end = offs[wid + 1];
    const float di = dinv[wid];
    const float4* __restrict__ hp = (const float4*)h;  // row = 16 float4

    float a[8] = {0.f, 0.f, 0.f, 0.f, 0.f, 0.f, 0.f, 0.f};
    int e = beg;
    for (; e + 16 <= end; e += 16) {
        int s0 = csr[e + q];
        int s1 = csr[e + 8 + q];
        float4 r0 = hp[(size_t)s0 * 16 + cc];
        float4 r1 = hp[(size_t)s1 * 16 + cc];
        const __half* h0 = (const __half*)&r0;
        const __half* h1 = (const __half*)&r1;
#pragma unroll
        for (int j = 0; j < 8; ++j) a[j] += __half2float(h0[j]);
#pragma unroll
        for (int j = 0; j < 8; ++j) a[j] += __half2float(h1[j]);
    }
    for (; e < end; e += 8) {
        const int last = end - 1;
        int i0 = e + q;
        float m0 = (i0 < end) ? 1.f : 0.f;
        int s0 = csr[min(i0, last)];
        float4 r0 = hp[(size_t)s0 * 16 + cc];
        const __half* h0 = (const __half*)&r0;
#pragma unroll
        for (int j = 0; j < 8; ++j) a[j] = fmaf(__half2float(h0[j]), m0, a[j]);
    }
#pragma unroll
    for (int j = 0; j < 8; ++j) {
        a[j] += __shfl_xor(a[j], 8);
        a[j] += __shfl_xor(a[j], 16);
        a[j] += __shfl_xor(a[j], 32);
    }
    {  // self-loop
        float4 rs = hp[(size_t)wid * 16 + cc];
        const __half* hs = (const __half*)&rs;
#pragma unroll
        for (int j = 0; j < 8; ++j) a[j] += __half2float(hs[j]);
    }
    float4 b0 = ((const float4*)bias)[2 * cc];
    float4 b1 = ((const float4*)bias)[2 * cc + 1];
    float z[8];
    z[0] = fmaf(di, a[0], b0.x); z[1] = fmaf(di, a[1], b0.y);
    z[2] = fmaf(di, a[2], b0.z); z[3] = fmaf(di, a[3], b0.w);
    z[4] = fmaf(di, a[4], b1.x); z[5] = fmaf(di, a[5], b1.y);
    z[6] = fmaf(di, a[6], b1.z); z[7] = fmaf(di, a[7], b1.w);
    if (RELU) {
#pragma unroll
        for (int j = 0; j < 8; ++j) z[j] = fmaxf(z[j], 0.f);
    }
    if (q == 0) {
        __half2 o[4] = {__float22half2_rn(make_float2(z[0], z[1])),
                        __float22half2_rn(make_float2(z[2], z[3])),
                        __float22half2_rn(make_float2(z[4], z[5])),
                        __float22half2_rn(make_float2(z[6], z[7]))};
        ((float4*)out)[(size_t)wid * 16 + cc] = *(float4*)o;
    }
}

// final agg (64 ch), channel-split: 4 lanes x 16B = 64B half-row; 16 slots; fp32 out.
__global__ __launch_bounds__(256) void agg64h(const __half* __restrict__ h,  // [N][64]
                                              const float* __restrict__ dinv,
                                              const int* __restrict__ offs,
                                              const int* __restrict__ csr,
                                              const float* __restrict__ bias,
                                              float* __restrict__ out, int N, int half) {
    const int wid = (blockIdx.x * 256 + threadIdx.x) >> 6;
    if (wid >= N) return;
    const int l = threadIdx.x & 63;
    const int q = l >> 2;           // edge slot 0..15
    const int cc = half * 4 + (l & 3);  // 16B chunk within full row (0..7)
    const int beg = offs[wid], end = offs[wid + 1];
    const float di = dinv[wid];
    const float4* __restrict__ hp = (const float4*)h;  // row = 8 float4

    float a[8] = {0.f, 0.f, 0.f, 0.f, 0.f, 0.f, 0.f, 0.f};
    int e = beg;
    for (; e + 32 <= end; e += 32) {
        int s0 = csr[e + q];
        int s1 = csr[e + 16 + q];
        float4 r0 = hp[(size_t)s0 * 8 + cc];
        float4 r1 = hp[(size_t)s1 * 8 + cc];
        const __half* h0 = (const __half*)&r0;
        const __half* h1 = (const __half*)&r1;
#pragma unroll
        for (int j = 0; j < 8; ++j) a[j] += __half2float(h0[j]);
#pragma unroll
        for (int j = 0; j < 8; ++j) a[j] += __half2float(h1[j]);
    }
    for (; e < end; e += 16) {
        const int last = end - 1;
        int i0 = e + q;
        float m0 = (i0 < end) ? 1.f : 0.f;
        int s0 = csr[min(i0, last)];
        float4 r0 = hp[(size_t)s0 * 8 + cc];
        const __half* h0 = (const __half*)&r0;
#pragma unroll
        for (int j = 0; j < 8; ++j) a[j] = fmaf(__half2float(h0[j]), m0, a[j]);
    }
#pragma unroll
    for (int j = 0; j < 8; ++j) {
        a[j] += __shfl_xor(a[j], 4);
        a[j] += __shfl_xor(a[j], 8);
        a[j] += __shfl_xor(a[j], 16);
        a[j] += __shfl_xor(a[j], 32);
    }
    {
        float4 rs = hp[(size_t)wid * 8 + cc];
        const __half* hs = (const __half*)&rs;
#pragma unroll
        for (int j = 0; j < 8; ++j) a[j] += __half2float(hs[j]);
    }
    float4 b0 = ((const float4*)bias)[2 * cc];
    float4 b1 = ((const float4*)bias)[2 * cc + 1];
    float z[8];
    z[0] = fmaf(di, a[0], b0.x); z[1] = fmaf(di, a[1], b0.y);
    z[2] = fmaf(di, a[2], b0.z); z[3] = fmaf(di, a[3], b0.w);
    z[4] = fmaf(di, a[4], b1.x); z[5] = fmaf(di, a[5], b1.y);
    z[6] = fmaf(di, a[6], b1.z); z[7] = fmaf(di, a[7], b1.w);
    if (q == 0) {
        ((float4*)out)[(size_t)wid * 16 + 2 * cc] = make_float4(z[0], z[1], z[2], z[3]);
        ((float4*)out)[(size_t)wid * 16 + 2 * cc + 1] = make_float4(z[4], z[5], z[6], z[7]);
    }
}

// ---------------- launch ----------------

extern "C" void kernel_launch(void* const* d_in, const int* in_sizes, int n_in,
                              void* d_out, int out_size, void* d_ws, size_t ws_size,
                              hipStream_t stream) {
    const float* x  = (const float*)d_in[0];
    const int*   ei = (const int*)d_in[1];
    const float* W1 = (const float*)d_in[2];
    const float* b1 = (const float*)d_in[3];
    const float* W2 = (const float*)d_in[4];
    const float* b2 = (const float*)d_in[5];
    const float* W3 = (const float*)d_in[6];
    const float* b3 = (const float*)d_in[7];

    const int N = in_sizes[0] / 128;
    const int E = in_sizes[1] / 2;
    const int* row = ei;       // sources
    const int* col = ei + E;   // targets

    const int NB = (N + BMASK) >> BSH;       // 256-node buckets
    const int B1 = (E + CHUNK - 1) / CHUNK;
    const int NBB1 = NB * B1;

    char* p = (char*)d_ws;
    auto alloc = [&](size_t bytes) {
        char* r = p;
        p += (bytes + 255) & ~(size_t)255;
        return r;
    };
    int*    offs  = (int*)alloc((size_t)(N + 1) * 4);
    float*  dinv  = (float*)alloc((size_t)N * 4);
    int*    histG = (int*)alloc((size_t)NBB1 * 4);
    int*    bsum  = (int*)alloc(1024 * 4);
    int*    ebuf  = (int*)alloc((size_t)E * 4);
    int*    csr   = (int*)alloc((size_t)E * 4);
    __half* bufA  = (__half*)alloc((size_t)N * 128 * 2);
    __half* bufB  = (__half*)alloc((size_t)N * 128 * 2);
    __half* wT1   = (__half*)alloc(16384 * 2);
    __half* wT2   = (__half*)alloc(16384 * 2);
    __half* wT3   = (__half*)alloc(8192 * 2);

    const int nsb = (NBB1 + 1023) / 1024;

    // CSR build
    hist_pass<<<B1, 256, 0, stream>>>(col, E, NB, B1, histG);
    scan_blocks<<<nsb, 256, 0, stream>>>(histG, NBB1, bsum);
    scan_single<<<1, 256, 0, stream>>>(bsum, nsb);
    scatter_pass<<<B1, 256, 0, stream>>>(row, col, E, NB, B1, histG, bsum, ebuf);
    build_csr<<<NB, 256, 0, stream>>>(ebuf, histG, bsum, NB, B1, N, E, offs, dinv, csr);

    prep_wT<<<160, 256, 0, stream>>>(W1, W2, W3, wT1, wT2, wT3);

    const int gTile = (N + 127) / 128;
    const int gAgg = (N + 3) / 4;

    // layer 1 (fused fp32->fp16 cast in GEMM); agg split into two channel halves
    gemm_x<<<gTile, 256, 0, stream>>>(x, wT1, dinv, bufA, N);
    agg128h<true><<<gAgg, 256, 0, stream>>>(bufA, dinv, offs, csr, b1, bufB, N, 0);
    agg128h<true><<<gAgg, 256, 0, stream>>>(bufA, dinv, offs, csr, b1, bufB, N, 1);

    // layer 2
    gemm_f16<128><<<gTile, 256, 0, stream>>>(bufB, wT2, dinv, bufA, N);
    agg128h<true><<<gAgg, 256, 0, stream>>>(bufA, dinv, offs, csr, b2, bufB, N, 0);
    agg128h<true><<<gAgg, 256, 0, stream>>>(bufA, dinv, offs, csr, b2, bufB, N, 1);

    // layer 3 (64 cols), final agg -> fp32 out, split halves
    gemm_f16<64><<<gTile, 256, 0, stream>>>(bufB, wT3, dinv, bufA, N);
    agg64h<<<gAgg, 256, 0, stream>>>(bufA, dinv, offs, csr, b3, (float*)d_out, N, 0);
    agg64h<<<gAgg, 256, 0, stream>>>(bufA, dinv, offs, csr, b3, (float*)d_out, N, 1);
}

// Round 11
// 301.200 us; speedup vs baseline: 1.1952x; 1.1952x over previous
//
#include <hip/hip_runtime.h>
#include <hip/hip_fp16.h>

// GCN 3-layer encoder. R11 = R10 with compile fix: nontemporal builtins need
// clang ext_vector types, not HIP_vector_type (float4). Otherwise identical:
// R8 full-row agg + nt hints on streamed csr/out + LDS-free gemm_f16 + R9 CSR.

#define K_DIM 128
#define CHUNK 4096
#define NBMAX 1024
#define BSH 8          // bucket shift: 256 nodes per bucket
#define BMASK 255

typedef _Float16 f16x8 __attribute__((ext_vector_type(8)));
typedef float f32x4 __attribute__((ext_vector_type(4)));

// ---------------- preprocessing: counting-sort CSR build ----------------

__global__ __launch_bounds__(256) void hist_pass(const int* __restrict__ col, int E,
                                                 int NB, int B1, int* __restrict__ histG) {
    __shared__ int h[NBMAX];
    const int tid = threadIdx.x;
    for (int i = tid; i < NB; i += 256) h[i] = 0;
    __syncthreads();
    const int base = blockIdx.x * CHUNK;
    const int bend = min(base + CHUNK, E);
    for (int idx = base + tid * 4; idx < bend; idx += 1024) {
        if (idx + 4 <= bend) {
            int4 c4 = *(const int4*)&col[idx];
            atomicAdd(&h[c4.x >> BSH], 1);
            atomicAdd(&h[c4.y >> BSH], 1);
            atomicAdd(&h[c4.z >> BSH], 1);
            atomicAdd(&h[c4.w >> BSH], 1);
        } else {
            for (int j = 0; j < 4 && idx + j < bend; ++j)
                atomicAdd(&h[col[idx + j] >> BSH], 1);
        }
    }
    __syncthreads();
    for (int i = tid; i < NB; i += 256) histG[(size_t)i * B1 + blockIdx.x] = h[i];
}

__global__ __launch_bounds__(256) void scan_blocks(int* __restrict__ data, int n,
                                                   int* __restrict__ bsum) {
    __shared__ int sh[256];
    const int tid = threadIdx.x;
    const int base = blockIdx.x * 1024;
    int v[4];
    int sum = 0;
#pragma unroll
    for (int j = 0; j < 4; ++j) {
        int i = base + tid * 4 + j;
        v[j] = (i < n) ? data[i] : 0;
        sum += v[j];
    }
    sh[tid] = sum;
    __syncthreads();
#pragma unroll
    for (int off = 1; off < 256; off <<= 1) {
        int t = (tid >= off) ? sh[tid - off] : 0;
        __syncthreads();
        sh[tid] += t;
        __syncthreads();
    }
    int run = (tid > 0) ? sh[tid - 1] : 0;
#pragma unroll
    for (int j = 0; j < 4; ++j) {
        int i = base + tid * 4 + j;
        if (i < n) data[i] = run;
        run += v[j];
    }
    if (tid == 255) bsum[blockIdx.x] = sh[255];
}

__global__ __launch_bounds__(256) void scan_single(int* __restrict__ data, int n) {
    __shared__ int sh[256];
    const int tid = threadIdx.x;
    int v[4];
    int sum = 0;
#pragma unroll
    for (int j = 0; j < 4; ++j) {
        int i = tid * 4 + j;
        v[j] = (i < n) ? data[i] : 0;
        sum += v[j];
    }
    sh[tid] = sum;
    __syncthreads();
#pragma unroll
    for (int off = 1; off < 256; off <<= 1) {
        int t = (tid >= off) ? sh[tid - off] : 0;
        __syncthreads();
        sh[tid] += t;
        __syncthreads();
    }
    int run = (tid > 0) ? sh[tid - 1] : 0;
#pragma unroll
    for (int j = 0; j < 4; ++j) {
        int i = tid * 4 + j;
        if (i < n) data[i] = run;
        run += v[j];
    }
}

// scatter with bsum folded: global cursor = histG[idx] + bsum[idx>>10]
__global__ __launch_bounds__(256) void scatter_pass(const int* __restrict__ row,
                                                    const int* __restrict__ col, int E,
                                                    int NB, int B1,
                                                    const int* __restrict__ histG,
                                                    const int* __restrict__ bsum,
                                                    int* __restrict__ ebuf) {
    __shared__ int cur[NBMAX];
    const int tid = threadIdx.x;
    for (int i = tid; i < NB; i += 256) {
        const size_t idx = (size_t)i * B1 + blockIdx.x;
        cur[i] = histG[idx] + bsum[idx >> 10];
    }
    __syncthreads();
    const int base = blockIdx.x * CHUNK;
    const int bend = min(base + CHUNK, E);
    for (int idx = base + tid * 4; idx < bend; idx += 1024) {
        if (idx + 4 <= bend) {
            int4 d4 = *(const int4*)&col[idx];
            int4 s4 = *(const int4*)&row[idx];
            int p0 = atomicAdd(&cur[d4.x >> BSH], 1);
            ebuf[p0] = (s4.x << BSH) | (d4.x & BMASK);
            int p1 = atomicAdd(&cur[d4.y >> BSH], 1);
            ebuf[p1] = (s4.y << BSH) | (d4.y & BMASK);
            int p2 = atomicAdd(&cur[d4.z >> BSH], 1);
            ebuf[p2] = (s4.z << BSH) | (d4.z & BMASK);
            int p3 = atomicAdd(&cur[d4.w >> BSH], 1);
            ebuf[p3] = (s4.w << BSH) | (d4.w & BMASK);
        } else {
            for (int j = 0; j < 4 && idx + j < bend; ++j) {
                int d = col[idx + j];
                int s = row[idx + j];
                int pos = atomicAdd(&cur[d >> BSH], 1);
                ebuf[pos] = (s << BSH) | (d & BMASK);
            }
        }
    }
}

__global__ __launch_bounds__(256) void build_csr(const int* __restrict__ ebuf,
                                                 const int* __restrict__ histG,
                                                 const int* __restrict__ bsum,
                                                 int NB, int B1, int N, int E,
                                                 int* __restrict__ offs,
                                                 float* __restrict__ dinv,
                                                 int* __restrict__ csr) {
    __shared__ int cnt[256];
    __shared__ int scn[256];
    __shared__ int curL[256];
    const int tid = threadIdx.x;
    const int b = blockIdx.x;
    const size_t iS = (size_t)b * B1;
    const int S = histG[iS] + bsum[iS >> 10];
    int T = E;
    if (b + 1 < NB) {
        const size_t iT = (size_t)(b + 1) * B1;
        T = histG[iT] + bsum[iT >> 10];
    }

    cnt[tid] = 0;
    __syncthreads();
    for (int i = S + tid; i < T; i += 256) atomicAdd(&cnt[ebuf[i] & BMASK], 1);
    __syncthreads();
    scn[tid] = cnt[tid];
    __syncthreads();
#pragma unroll
    for (int off = 1; off < 256; off <<= 1) {
        int t = (tid >= off) ? scn[tid - off] : 0;
        __syncthreads();
        scn[tid] += t;
        __syncthreads();
    }
    {
        int exc = (tid > 0) ? scn[tid - 1] : 0;
        int node = b * 256 + tid;
        if (node < N) {
            offs[node] = S + exc;
            dinv[node] = rsqrtf((float)(cnt[tid] + 1));
        }
        curL[tid] = S + exc;
    }
    if (b == 0 && tid == 0) offs[N] = E;
    __syncthreads();
    for (int i = S + tid; i < T; i += 256) {
        int p = ebuf[i];
        int pos = atomicAdd(&curL[p & BMASK], 1);
        csr[pos] = p >> BSH;
    }
}

// W[k][nc] fp32 -> wT[n*128 + k] fp16 (transposed), all three weights
__global__ void prep_wT(const float* __restrict__ W1, const float* __restrict__ W2,
                        const float* __restrict__ W3, __half* __restrict__ wT1,
                        __half* __restrict__ wT2, __half* __restrict__ wT3) {
    int tid = blockIdx.x * 256 + threadIdx.x;
    if (tid < 16384) {
        int n = tid >> 7, k = tid & 127;
        wT1[tid] = __float2half(W1[k * 128 + n]);
    } else if (tid < 32768) {
        int t = tid - 16384;
        int n = t >> 7, k = t & 127;
        wT2[t] = __float2half(W2[k * 128 + n]);
    } else if (tid < 40960) {
        int t = tid - 32768;
        int n = t >> 7, k = t & 127;  // n in [0,64)
        wT3[t] = __float2half(W3[k * 64 + n]);
    }
}

// ------------- layer-1 GEMM with fused fp32->fp16 cast -------------

__global__ __launch_bounds__(256) void gemm_x(const float* __restrict__ X,    // [M][128] fp32
                                              const __half* __restrict__ wT,  // [128][128]
                                              const float* __restrict__ dinv,
                                              __half* __restrict__ out, int M) {
    const int tid = threadIdx.x;
    const int wave = tid >> 6;
    const int l = tid & 63;
    const int lm = l & 15;
    const int kg = l >> 4;
    const int row0 = blockIdx.x * 128 + wave * 32;

    f32x4 acc[2][8];
#pragma unroll
    for (int mt = 0; mt < 2; ++mt)
#pragma unroll
        for (int nt = 0; nt < 8; ++nt) acc[mt][nt] = {0.f, 0.f, 0.f, 0.f};

    const int m0 = row0 + lm;
    const int m1 = row0 + 16 + lm;
    const int mc0 = min(m0, M - 1);
    const int mc1 = min(m1, M - 1);

#pragma unroll
    for (int ks = 0; ks < 4; ++ks) {
        const int k0 = ks * 32 + kg * 8;
        f32x4 u0 = __builtin_nontemporal_load((const f32x4*)&X[(size_t)mc0 * 128 + k0]);
        f32x4 u1 = __builtin_nontemporal_load((const f32x4*)&X[(size_t)mc0 * 128 + k0 + 4]);
        f32x4 u2 = __builtin_nontemporal_load((const f32x4*)&X[(size_t)mc1 * 128 + k0]);
        f32x4 u3 = __builtin_nontemporal_load((const f32x4*)&X[(size_t)mc1 * 128 + k0 + 4]);
        f16x8 b0 = {(_Float16)u0.x, (_Float16)u0.y, (_Float16)u0.z, (_Float16)u0.w,
                    (_Float16)u1.x, (_Float16)u1.y, (_Float16)u1.z, (_Float16)u1.w};
        f16x8 b1 = {(_Float16)u2.x, (_Float16)u2.y, (_Float16)u2.z, (_Float16)u2.w,
                    (_Float16)u3.x, (_Float16)u3.y, (_Float16)u3.z, (_Float16)u3.w};
#pragma unroll
        for (int nt = 0; nt < 8; ++nt) {
            f16x8 a = *(const f16x8*)&wT[(size_t)(nt * 16 + lm) * 128 + k0];
            acc[0][nt] = __builtin_amdgcn_mfma_f32_16x16x32_f16(a, b0, acc[0][nt], 0, 0, 0);
            acc[1][nt] = __builtin_amdgcn_mfma_f32_16x16x32_f16(a, b1, acc[1][nt], 0, 0, 0);
        }
    }

#pragma unroll
    for (int mt = 0; mt < 2; ++mt) {
        const int m = (mt == 0) ? m0 : m1;
        if (m < M) {
            const float dv = dinv[m];
#pragma unroll
            for (int nt = 0; nt < 8; ++nt) {
                float z0 = acc[mt][nt][0] * dv, z1 = acc[mt][nt][1] * dv;
                float z2 = acc[mt][nt][2] * dv, z3 = acc[mt][nt][3] * dv;
                __half2 o[2] = {__float22half2_rn(make_float2(z0, z1)),
                                __float22half2_rn(make_float2(z2, z3))};
                *(float2*)&out[(size_t)m * 128 + nt * 16 + kg * 4] = *(float2*)o;
            }
        }
    }
}

// ------------- fp16 GEMM (layers 2,3), no LDS: wT direct from global (L2-hot) -------------

template <int NCOLS>
__global__ __launch_bounds__(256) void gemm_f16(const __half* __restrict__ A,   // [M][128]
                                                const __half* __restrict__ wT,  // [NCOLS][128]
                                                const float* __restrict__ dinv,
                                                __half* __restrict__ out, int M) {
    constexpr int NT = NCOLS / 16;  // 8 or 4
    const int tid = threadIdx.x;
    const int wave = tid >> 6;
    const int l = tid & 63;
    const int lm = l & 15;
    const int kg = l >> 4;
    const int row0 = blockIdx.x * 128 + wave * 32;

    f32x4 acc[2][NT];
#pragma unroll
    for (int mt = 0; mt < 2; ++mt)
#pragma unroll
        for (int nt = 0; nt < NT; ++nt) acc[mt][nt] = {0.f, 0.f, 0.f, 0.f};

    const int m0 = row0 + lm;
    const int m1 = row0 + 16 + lm;
    const int mc0 = min(m0, M - 1);
    const int mc1 = min(m1, M - 1);

#pragma unroll
    for (int ks = 0; ks < 4; ++ks) {
        const int k0 = ks * 32 + kg * 8;
        f16x8 b0 = __builtin_nontemporal_load((const f16x8*)&A[(size_t)mc0 * 128 + k0]);
        f16x8 b1 = __builtin_nontemporal_load((const f16x8*)&A[(size_t)mc1 * 128 + k0]);
#pragma unroll
        for (int nt = 0; nt < NT; ++nt) {
            f16x8 a = *(const f16x8*)&wT[(size_t)(nt * 16 + lm) * 128 + k0];
            acc[0][nt] = __builtin_amdgcn_mfma_f32_16x16x32_f16(a, b0, acc[0][nt], 0, 0, 0);
            acc[1][nt] = __builtin_amdgcn_mfma_f32_16x16x32_f16(a, b1, acc[1][nt], 0, 0, 0);
        }
    }

#pragma unroll
    for (int mt = 0; mt < 2; ++mt) {
        const int m = (mt == 0) ? m0 : m1;
        if (m < M) {
            const float dv = dinv[m];
#pragma unroll
            for (int nt = 0; nt < NT; ++nt) {
                float z0 = acc[mt][nt][0] * dv, z1 = acc[mt][nt][1] * dv;
                float z2 = acc[mt][nt][2] * dv, z3 = acc[mt][nt][3] * dv;
                __half2 o[2] = {__float22half2_rn(make_float2(z0, z1)),
                                __float22half2_rn(make_float2(z2, z3))};
                *(float2*)&out[(size_t)m * NCOLS + nt * 16 + kg * 4] = *(float2*)o;
            }
        }
    }
}

// ------------- aggregation: quarter-wave float4 gather, norm pre-folded -------------
// 16 edges/iter main loop (4 gathers in flight), masked 8-wide tail.
// csr loads + output stores nontemporal (keep L2 for the h gather target).

template <bool RELU>
__global__ __launch_bounds__(256) void agg128(const __half* __restrict__ h,  // h_pre [N][128]
                                              const float* __restrict__ dinv,
                                              const int* __restrict__ offs,
                                              const int* __restrict__ csr,
                                              const float* __restrict__ bias,
                                              __half* __restrict__ out, int N) {
    const int wid = (blockIdx.x * 256 + threadIdx.x) >> 6;
    if (wid >= N) return;
    const int l = threadIdx.x & 63;
    const int q = l >> 4;  // edge slot
    const int c = l & 15;  // 16B chunk (8 channels)
    const int beg = offs[wid], end = offs[wid + 1];
    const float di = dinv[wid];
    const f32x4* __restrict__ hp = (const f32x4*)h;  // row = 16 chunks

    float a[8] = {0.f, 0.f, 0.f, 0.f, 0.f, 0.f, 0.f, 0.f};
    int e = beg;
    for (; e + 16 <= end; e += 16) {
        int s0 = __builtin_nontemporal_load(&csr[e + q]);
        int s1 = __builtin_nontemporal_load(&csr[e + 4 + q]);
        int s2 = __builtin_nontemporal_load(&csr[e + 8 + q]);
        int s3 = __builtin_nontemporal_load(&csr[e + 12 + q]);
        f32x4 r0 = hp[(size_t)s0 * 16 + c];
        f32x4 r1 = hp[(size_t)s1 * 16 + c];
        f32x4 r2 = hp[(size_t)s2 * 16 + c];
        f32x4 r3 = hp[(size_t)s3 * 16 + c];
        const __half* h0 = (const __half*)&r0;
        const __half* h1 = (const __half*)&r1;
        const __half* h2 = (const __half*)&r2;
        const __half* h3 = (const __half*)&r3;
#pragma unroll
        for (int j = 0; j < 8; ++j) a[j] += __half2float(h0[j]);
#pragma unroll
        for (int j = 0; j < 8; ++j) a[j] += __half2float(h1[j]);
#pragma unroll
        for (int j = 0; j < 8; ++j) a[j] += __half2float(h2[j]);
#pragma unroll
        for (int j = 0; j < 8; ++j) a[j] += __half2float(h3[j]);
    }
    for (; e < end; e += 8) {
        const int last = end - 1;
        int i0 = e + q, i1 = e + 4 + q;
        float m0 = (i0 < end) ? 1.f : 0.f;
        float m1 = (i1 < end) ? 1.f : 0.f;
        int s0 = csr[min(i0, last)];
        int s1 = csr[min(i1, last)];
        f32x4 r0 = hp[(size_t)s0 * 16 + c];
        f32x4 r1 = hp[(size_t)s1 * 16 + c];
        const __half* h0 = (const __half*)&r0;
        const __half* h1 = (const __half*)&r1;
#pragma unroll
        for (int j = 0; j < 8; ++j) a[j] = fmaf(__half2float(h0[j]), m0, a[j]);
#pragma unroll
        for (int j = 0; j < 8; ++j) a[j] = fmaf(__half2float(h1[j]), m1, a[j]);
    }
#pragma unroll
    for (int j = 0; j < 8; ++j) {
        a[j] += __shfl_xor(a[j], 16);
        a[j] += __shfl_xor(a[j], 32);
    }
    {  // self-loop
        f32x4 rs = hp[(size_t)wid * 16 + c];
        const __half* hs = (const __half*)&rs;
#pragma unroll
        for (int j = 0; j < 8; ++j) a[j] += __half2float(hs[j]);
    }
    float4 b0 = ((const float4*)bias)[2 * c];
    float4 b1 = ((const float4*)bias)[2 * c + 1];
    float z[8];
    z[0] = fmaf(di, a[0], b0.x); z[1] = fmaf(di, a[1], b0.y);
    z[2] = fmaf(di, a[2], b0.z); z[3] = fmaf(di, a[3], b0.w);
    z[4] = fmaf(di, a[4], b1.x); z[5] = fmaf(di, a[5], b1.y);
    z[6] = fmaf(di, a[6], b1.z); z[7] = fmaf(di, a[7], b1.w);
    if (RELU) {
#pragma unroll
        for (int j = 0; j < 8; ++j) z[j] = fmaxf(z[j], 0.f);
    }
    if (q == 0) {
        __half2 o[4] = {__float22half2_rn(make_float2(z[0], z[1])),
                        __float22half2_rn(make_float2(z[2], z[3])),
                        __float22half2_rn(make_float2(z[4], z[5])),
                        __float22half2_rn(make_float2(z[6], z[7]))};
        __builtin_nontemporal_store(*(f32x4*)o, (f32x4*)out + (size_t)wid * 16 + c);
    }
}

// C=64 final agg: 8 lanes x 16B per edge; 16 edges/iter (2 gathers); fp32 output.
__global__ __launch_bounds__(256) void agg64(const __half* __restrict__ h,  // [N][64]
                                             const float* __restrict__ dinv,
                                             const int* __restrict__ offs,
                                             const int* __restrict__ csr,
                                             const float* __restrict__ bias,
                                             float* __restrict__ out, int N) {
    const int wid = (blockIdx.x * 256 + threadIdx.x) >> 6;
    if (wid >= N) return;
    const int l = threadIdx.x & 63;
    const int q = l >> 3;  // edge slot 0..7
    const int c = l & 7;   // 16B chunk
    const int beg = offs[wid], end = offs[wid + 1];
    const float di = dinv[wid];
    const f32x4* __restrict__ hp = (const f32x4*)h;  // row = 8 chunks

    float a[8] = {0.f, 0.f, 0.f, 0.f, 0.f, 0.f, 0.f, 0.f};
    int e = beg;
    for (; e + 16 <= end; e += 16) {
        int s0 = __builtin_nontemporal_load(&csr[e + q]);
        int s1 = __builtin_nontemporal_load(&csr[e + 8 + q]);
        f32x4 r0 = hp[(size_t)s0 * 8 + c];
        f32x4 r1 = hp[(size_t)s1 * 8 + c];
        const __half* h0 = (const __half*)&r0;
        const __half* h1 = (const __half*)&r1;
#pragma unroll
        for (int j = 0; j < 8; ++j) a[j] += __half2float(h0[j]);
#pragma unroll
        for (int j = 0; j < 8; ++j) a[j] += __half2float(h1[j]);
    }
    for (; e < end; e += 8) {
        const int last = end - 1;
        int i0 = e + q;
        float m0 = (i0 < end) ? 1.f : 0.f;
        int s0 = csr[min(i0, last)];
        f32x4 r0 = hp[(size_t)s0 * 8 + c];
        const __half* h0 = (const __half*)&r0;
#pragma unroll
        for (int j = 0; j < 8; ++j) a[j] = fmaf(__half2float(h0[j]), m0, a[j]);
    }
#pragma unroll
    for (int j = 0; j < 8; ++j) {
        a[j] += __shfl_xor(a[j], 8);
        a[j] += __shfl_xor(a[j], 16);
        a[j] += __shfl_xor(a[j], 32);
    }
    {
        f32x4 rs = hp[(size_t)wid * 8 + c];
        const __half* hs = (const __half*)&rs;
#pragma unroll
        for (int j = 0; j < 8; ++j) a[j] += __half2float(hs[j]);
    }
    float4 b0 = ((const float4*)bias)[2 * c];
    float4 b1 = ((const float4*)bias)[2 * c + 1];
    f32x4 z0v = {fmaf(di, a[0], b0.x), fmaf(di, a[1], b0.y),
                 fmaf(di, a[2], b0.z), fmaf(di, a[3], b0.w)};
    f32x4 z1v = {fmaf(di, a[4], b1.x), fmaf(di, a[5], b1.y),
                 fmaf(di, a[6], b1.z), fmaf(di, a[7], b1.w)};
    if (q == 0) {
        __builtin_nontemporal_store(z0v, (f32x4*)out + (size_t)wid * 16 + 2 * c);
        __builtin_nontemporal_store(z1v, (f32x4*)out + (size_t)wid * 16 + 2 * c + 1);
    }
}

// ---------------- launch ----------------

extern "C" void kernel_launch(void* const* d_in, const int* in_sizes, int n_in,
                              void* d_out, int out_size, void* d_ws, size_t ws_size,
                              hipStream_t stream) {
    const float* x  = (const float*)d_in[0];
    const int*   ei = (const int*)d_in[1];
    const float* W1 = (const float*)d_in[2];
    const float* b1 = (const float*)d_in[3];
    const float* W2 = (const float*)d_in[4];
    const float* b2 = (const float*)d_in[5];
    const float* W3 = (const float*)d_in[6];
    const float* b3 = (const float*)d_in[7];

    const int N = in_sizes[0] / 128;
    const int E = in_sizes[1] / 2;
    const int* row = ei;       // sources
    const int* col = ei + E;   // targets

    const int NB = (N + BMASK) >> BSH;       // 256-node buckets
    const int B1 = (E + CHUNK - 1) / CHUNK;
    const int NBB1 = NB * B1;

    char* p = (char*)d_ws;
    auto alloc = [&](size_t bytes) {
        char* r = p;
        p += (bytes + 255) & ~(size_t)255;
        return r;
    };
    int*    offs  = (int*)alloc((size_t)(N + 1) * 4);
    float*  dinv  = (float*)alloc((size_t)N * 4);
    int*    histG = (int*)alloc((size_t)NBB1 * 4);
    int*    bsum  = (int*)alloc(1024 * 4);
    int*    ebuf  = (int*)alloc((size_t)E * 4);
    int*    csr   = (int*)alloc((size_t)E * 4);
    __half* bufA  = (__half*)alloc((size_t)N * 128 * 2);
    __half* bufB  = (__half*)alloc((size_t)N * 128 * 2);
    __half* wT1   = (__half*)alloc(16384 * 2);
    __half* wT2   = (__half*)alloc(16384 * 2);
    __half* wT3   = (__half*)alloc(8192 * 2);

    const int nsb = (NBB1 + 1023) / 1024;

    // CSR build
    hist_pass<<<B1, 256, 0, stream>>>(col, E, NB, B1, histG);
    scan_blocks<<<nsb, 256, 0, stream>>>(histG, NBB1, bsum);
    scan_single<<<1, 256, 0, stream>>>(bsum, nsb);
    scatter_pass<<<B1, 256, 0, stream>>>(row, col, E, NB, B1, histG, bsum, ebuf);
    build_csr<<<NB, 256, 0, stream>>>(ebuf, histG, bsum, NB, B1, N, E, offs, dinv, csr);

    prep_wT<<<160, 256, 0, stream>>>(W1, W2, W3, wT1, wT2, wT3);

    const int gTile = (N + 127) / 128;
    const int gAgg = (N + 3) / 4;

    // layer 1 (fused fp32->fp16 cast in GEMM)
    gemm_x<<<gTile, 256, 0, stream>>>(x, wT1, dinv, bufA, N);
    agg128<true><<<gAgg, 256, 0, stream>>>(bufA, dinv, offs, csr, b1, bufB, N);

    // layer 2
    gemm_f16<128><<<gTile, 256, 0, stream>>>(bufB, wT2, dinv, bufA, N);
    agg128<true><<<gAgg, 256, 0, stream>>>(bufA, dinv, offs, csr, b2, bufB, N);

    // layer 3 (64 cols), final agg -> fp32 out
    gemm_f16<64><<<gTile, 256, 0, stream>>>(bufB, wT3, dinv, bufA, N);
    agg64<<<gAgg, 256, 0, stream>>>(bufA, dinv, offs, csr, b3, (float*)d_out, N);
}

// Round 12
// 272.394 us; speedup vs baseline: 1.3216x; 1.1058x over previous
//
#include <hip/hip_runtime.h>
#include <hip/hip_fp16.h>

// GCN 3-layer encoder. R12 = R8 champion config exactly (best measured: 280us)
// + int4 edge reads in hist/scatter (isolated safe micro-opt from R9 bundle).
// Reverted from R11: no nt hints (agg-out nt store evicted data the next GEMM
// reads -> regression), gemm_f16 back to LDS-staged wT.
// - CSR build: 2-level counting sort (no global atomics), 256-node buckets.
// - GEMM: fp16 MFMA 16x16x32, swapped operands, fp32 acc, epilogue *dinv -> fp16.
// - Agg: out[i] = di*(sum_e h_pre[src] + h_pre[i]) + b; quarter-wave 256B row
//   gather, 16 edges/iter (4 gathers in flight). Pinned at the memory-service
//   floor (61us) across 6 attack variants — do not touch.

#define K_DIM 128
#define CHUNK 8192
#define NBMAX 1024
#define BSH 8          // bucket shift: 256 nodes per bucket
#define BMASK 255

typedef _Float16 f16x8 __attribute__((ext_vector_type(8)));
typedef float f32x4 __attribute__((ext_vector_type(4)));

// ---------------- preprocessing: counting-sort CSR build ----------------

__global__ __launch_bounds__(256) void hist_pass(const int* __restrict__ col, int E,
                                                 int NB, int B1, int* __restrict__ histG) {
    __shared__ int h[NBMAX];
    const int tid = threadIdx.x;
    for (int i = tid; i < NB; i += 256) h[i] = 0;
    __syncthreads();
    const int base = blockIdx.x * CHUNK;
    const int bend = min(base + CHUNK, E);
    for (int idx = base + tid * 4; idx < bend; idx += 1024) {
        if (idx + 4 <= bend) {
            int4 c4 = *(const int4*)&col[idx];
            atomicAdd(&h[c4.x >> BSH], 1);
            atomicAdd(&h[c4.y >> BSH], 1);
            atomicAdd(&h[c4.z >> BSH], 1);
            atomicAdd(&h[c4.w >> BSH], 1);
        } else {
            for (int j = 0; j < 4 && idx + j < bend; ++j)
                atomicAdd(&h[col[idx + j] >> BSH], 1);
        }
    }
    __syncthreads();
    for (int i = tid; i < NB; i += 256) histG[(size_t)i * B1 + blockIdx.x] = h[i];
}

__global__ __launch_bounds__(256) void scan_blocks(int* __restrict__ data, int n,
                                                   int* __restrict__ bsum) {
    __shared__ int sh[256];
    const int tid = threadIdx.x;
    const int base = blockIdx.x * 1024;
    int v[4];
    int sum = 0;
#pragma unroll
    for (int j = 0; j < 4; ++j) {
        int i = base + tid * 4 + j;
        v[j] = (i < n) ? data[i] : 0;
        sum += v[j];
    }
    sh[tid] = sum;
    __syncthreads();
#pragma unroll
    for (int off = 1; off < 256; off <<= 1) {
        int t = (tid >= off) ? sh[tid - off] : 0;
        __syncthreads();
        sh[tid] += t;
        __syncthreads();
    }
    int run = (tid > 0) ? sh[tid - 1] : 0;
#pragma unroll
    for (int j = 0; j < 4; ++j) {
        int i = base + tid * 4 + j;
        if (i < n) data[i] = run;
        run += v[j];
    }
    if (tid == 255) bsum[blockIdx.x] = sh[255];
}

__global__ __launch_bounds__(256) void scan_single(int* __restrict__ data, int n) {
    __shared__ int sh[256];
    const int tid = threadIdx.x;
    int v[4];
    int sum = 0;
#pragma unroll
    for (int j = 0; j < 4; ++j) {
        int i = tid * 4 + j;
        v[j] = (i < n) ? data[i] : 0;
        sum += v[j];
    }
    sh[tid] = sum;
    __syncthreads();
#pragma unroll
    for (int off = 1; off < 256; off <<= 1) {
        int t = (tid >= off) ? sh[tid - off] : 0;
        __syncthreads();
        sh[tid] += t;
        __syncthreads();
    }
    int run = (tid > 0) ? sh[tid - 1] : 0;
#pragma unroll
    for (int j = 0; j < 4; ++j) {
        int i = tid * 4 + j;
        if (i < n) data[i] = run;
        run += v[j];
    }
}

// scatter with bsum folded: global cursor = histG[idx] + bsum[idx>>10]
__global__ __launch_bounds__(256) void scatter_pass(const int* __restrict__ row,
                                                    const int* __restrict__ col, int E,
                                                    int NB, int B1,
                                                    const int* __restrict__ histG,
                                                    const int* __restrict__ bsum,
                                                    int* __restrict__ ebuf) {
    __shared__ int cur[NBMAX];
    const int tid = threadIdx.x;
    for (int i = tid; i < NB; i += 256) {
        const size_t idx = (size_t)i * B1 + blockIdx.x;
        cur[i] = histG[idx] + bsum[idx >> 10];
    }
    __syncthreads();
    const int base = blockIdx.x * CHUNK;
    const int bend = min(base + CHUNK, E);
    for (int idx = base + tid * 4; idx < bend; idx += 1024) {
        if (idx + 4 <= bend) {
            int4 d4 = *(const int4*)&col[idx];
            int4 s4 = *(const int4*)&row[idx];
            int p0 = atomicAdd(&cur[d4.x >> BSH], 1);
            ebuf[p0] = (s4.x << BSH) | (d4.x & BMASK);
            int p1 = atomicAdd(&cur[d4.y >> BSH], 1);
            ebuf[p1] = (s4.y << BSH) | (d4.y & BMASK);
            int p2 = atomicAdd(&cur[d4.z >> BSH], 1);
            ebuf[p2] = (s4.z << BSH) | (d4.z & BMASK);
            int p3 = atomicAdd(&cur[d4.w >> BSH], 1);
            ebuf[p3] = (s4.w << BSH) | (d4.w & BMASK);
        } else {
            for (int j = 0; j < 4 && idx + j < bend; ++j) {
                int d = col[idx + j];
                int s = row[idx + j];
                int pos = atomicAdd(&cur[d >> BSH], 1);
                ebuf[pos] = (s << BSH) | (d & BMASK);
            }
        }
    }
}

__global__ __launch_bounds__(256) void build_csr(const int* __restrict__ ebuf,
                                                 const int* __restrict__ histG,
                                                 const int* __restrict__ bsum,
                                                 int NB, int B1, int N, int E,
                                                 int* __restrict__ offs,
                                                 float* __restrict__ dinv,
                                                 int* __restrict__ csr) {
    __shared__ int cnt[256];
    __shared__ int scn[256];
    __shared__ int curL[256];
    const int tid = threadIdx.x;
    const int b = blockIdx.x;
    const size_t iS = (size_t)b * B1;
    const int S = histG[iS] + bsum[iS >> 10];
    int T = E;
    if (b + 1 < NB) {
        const size_t iT = (size_t)(b + 1) * B1;
        T = histG[iT] + bsum[iT >> 10];
    }

    cnt[tid] = 0;
    __syncthreads();
    for (int i = S + tid; i < T; i += 256) atomicAdd(&cnt[ebuf[i] & BMASK], 1);
    __syncthreads();
    scn[tid] = cnt[tid];
    __syncthreads();
#pragma unroll
    for (int off = 1; off < 256; off <<= 1) {
        int t = (tid >= off) ? scn[tid - off] : 0;
        __syncthreads();
        scn[tid] += t;
        __syncthreads();
    }
    {
        int exc = (tid > 0) ? scn[tid - 1] : 0;
        int node = b * 256 + tid;
        if (node < N) {
            offs[node] = S + exc;
            dinv[node] = rsqrtf((float)(cnt[tid] + 1));
        }
        curL[tid] = S + exc;
    }
    if (b == 0 && tid == 0) offs[N] = E;
    __syncthreads();
    for (int i = S + tid; i < T; i += 256) {
        int p = ebuf[i];
        int pos = atomicAdd(&curL[p & BMASK], 1);
        csr[pos] = p >> BSH;
    }
}

// W[k][nc] fp32 -> wT[n*128 + k] fp16 (transposed), all three weights
__global__ void prep_wT(const float* __restrict__ W1, const float* __restrict__ W2,
                        const float* __restrict__ W3, __half* __restrict__ wT1,
                        __half* __restrict__ wT2, __half* __restrict__ wT3) {
    int tid = blockIdx.x * 256 + threadIdx.x;
    if (tid < 16384) {
        int n = tid >> 7, k = tid & 127;
        wT1[tid] = __float2half(W1[k * 128 + n]);
    } else if (tid < 32768) {
        int t = tid - 16384;
        int n = t >> 7, k = t & 127;
        wT2[t] = __float2half(W2[k * 128 + n]);
    } else if (tid < 40960) {
        int t = tid - 32768;
        int n = t >> 7, k = t & 127;  // n in [0,64)
        wT3[t] = __float2half(W3[k * 64 + n]);
    }
}

// ------------- layer-1 GEMM with fused fp32->fp16 cast -------------

__global__ __launch_bounds__(256) void gemm_x(const float* __restrict__ X,    // [M][128] fp32
                                              const __half* __restrict__ wT,  // [128][128]
                                              const float* __restrict__ dinv,
                                              __half* __restrict__ out, int M) {
    const int tid = threadIdx.x;
    const int wave = tid >> 6;
    const int l = tid & 63;
    const int lm = l & 15;
    const int kg = l >> 4;
    const int row0 = blockIdx.x * 128 + wave * 32;

    f32x4 acc[2][8];
#pragma unroll
    for (int mt = 0; mt < 2; ++mt)
#pragma unroll
        for (int nt = 0; nt < 8; ++nt) acc[mt][nt] = {0.f, 0.f, 0.f, 0.f};

    const int m0 = row0 + lm;
    const int m1 = row0 + 16 + lm;
    const int mc0 = min(m0, M - 1);
    const int mc1 = min(m1, M - 1);

#pragma unroll
    for (int ks = 0; ks < 4; ++ks) {
        const int k0 = ks * 32 + kg * 8;
        float4 u0 = *(const float4*)&X[(size_t)mc0 * 128 + k0];
        float4 u1 = *(const float4*)&X[(size_t)mc0 * 128 + k0 + 4];
        float4 u2 = *(const float4*)&X[(size_t)mc1 * 128 + k0];
        float4 u3 = *(const float4*)&X[(size_t)mc1 * 128 + k0 + 4];
        f16x8 b0 = {(_Float16)u0.x, (_Float16)u0.y, (_Float16)u0.z, (_Float16)u0.w,
                    (_Float16)u1.x, (_Float16)u1.y, (_Float16)u1.z, (_Float16)u1.w};
        f16x8 b1 = {(_Float16)u2.x, (_Float16)u2.y, (_Float16)u2.z, (_Float16)u2.w,
                    (_Float16)u3.x, (_Float16)u3.y, (_Float16)u3.z, (_Float16)u3.w};
#pragma unroll
        for (int nt = 0; nt < 8; ++nt) {
            f16x8 a = *(const f16x8*)&wT[(size_t)(nt * 16 + lm) * 128 + k0];
            acc[0][nt] = __builtin_amdgcn_mfma_f32_16x16x32_f16(a, b0, acc[0][nt], 0, 0, 0);
            acc[1][nt] = __builtin_amdgcn_mfma_f32_16x16x32_f16(a, b1, acc[1][nt], 0, 0, 0);
        }
    }

#pragma unroll
    for (int mt = 0; mt < 2; ++mt) {
        const int m = (mt == 0) ? m0 : m1;
        if (m < M) {
            const float dv = dinv[m];
#pragma unroll
            for (int nt = 0; nt < 8; ++nt) {
                float z0 = acc[mt][nt][0] * dv, z1 = acc[mt][nt][1] * dv;
                float z2 = acc[mt][nt][2] * dv, z3 = acc[mt][nt][3] * dv;
                __half2 o[2] = {__float22half2_rn(make_float2(z0, z1)),
                                __float22half2_rn(make_float2(z2, z3))};
                *(float2*)&out[(size_t)m * 128 + nt * 16 + kg * 4] = *(float2*)o;
            }
        }
    }
}

// ------------- fp16 GEMM (layers 2,3): out = (A @ W') * dinv, fp16 out -------------

template <int NCOLS>
__global__ __launch_bounds__(256) void gemm_f16(const __half* __restrict__ A,   // [M][128]
                                                const __half* __restrict__ wT,  // [NCOLS][128]
                                                const float* __restrict__ dinv,
                                                __half* __restrict__ out, int M) {
    constexpr int NT = NCOLS / 16;  // 8 or 4
    __shared__ __half sWT[NCOLS][136];  // pad +8 halves

    const int tid = threadIdx.x;
    for (int idx = tid; idx < NCOLS * 16; idx += 256) {
        int n = idx >> 4, kc = (idx & 15) * 8;
        *(float4*)&sWT[n][kc] = *(const float4*)&wT[n * 128 + kc];
    }
    __syncthreads();

    const int wave = tid >> 6;
    const int l = tid & 63;
    const int lm = l & 15;
    const int kg = l >> 4;
    const int row0 = blockIdx.x * 128 + wave * 32;

    f32x4 acc[2][NT];
#pragma unroll
    for (int mt = 0; mt < 2; ++mt)
#pragma unroll
        for (int nt = 0; nt < NT; ++nt) acc[mt][nt] = {0.f, 0.f, 0.f, 0.f};

    const int m0 = row0 + lm;
    const int m1 = row0 + 16 + lm;
    const int mc0 = min(m0, M - 1);
    const int mc1 = min(m1, M - 1);

#pragma unroll
    for (int ks = 0; ks < 4; ++ks) {
        const int k0 = ks * 32 + kg * 8;
        f16x8 b0 = *(const f16x8*)&A[(size_t)mc0 * 128 + k0];
        f16x8 b1 = *(const f16x8*)&A[(size_t)mc1 * 128 + k0];
#pragma unroll
        for (int nt = 0; nt < NT; ++nt) {
            f16x8 a = *(const f16x8*)&sWT[nt * 16 + lm][k0];
            acc[0][nt] = __builtin_amdgcn_mfma_f32_16x16x32_f16(a, b0, acc[0][nt], 0, 0, 0);
            acc[1][nt] = __builtin_amdgcn_mfma_f32_16x16x32_f16(a, b1, acc[1][nt], 0, 0, 0);
        }
    }

#pragma unroll
    for (int mt = 0; mt < 2; ++mt) {
        const int m = (mt == 0) ? m0 : m1;
        if (m < M) {
            const float dv = dinv[m];
#pragma unroll
            for (int nt = 0; nt < NT; ++nt) {
                float z0 = acc[mt][nt][0] * dv, z1 = acc[mt][nt][1] * dv;
                float z2 = acc[mt][nt][2] * dv, z3 = acc[mt][nt][3] * dv;
                __half2 o[2] = {__float22half2_rn(make_float2(z0, z1)),
                                __float22half2_rn(make_float2(z2, z3))};
                *(float2*)&out[(size_t)m * NCOLS + nt * 16 + kg * 4] = *(float2*)o;
            }
        }
    }
}

// ------------- aggregation: quarter-wave float4 gather, norm pre-folded -------------
// Main loop 16 edges/iter (4 independent row gathers per lane), masked 8-wide tail.

template <bool RELU>
__global__ __launch_bounds__(256) void agg128(const __half* __restrict__ h,  // h_pre [N][128]
                                              const float* __restrict__ dinv,
                                              const int* __restrict__ offs,
                                              const int* __restrict__ csr,
                                              const float* __restrict__ bias,
                                              __half* __restrict__ out, int N) {
    const int wid = (blockIdx.x * 256 + threadIdx.x) >> 6;
    if (wid >= N) return;
    const int l = threadIdx.x & 63;
    const int q = l >> 4;  // edge slot
    const int c = l & 15;  // 16B chunk (8 channels)
    const int beg = offs[wid], end = offs[wid + 1];
    const float di = dinv[wid];
    const float4* __restrict__ hp = (const float4*)h;  // row = 16 float4

    float a[8] = {0.f, 0.f, 0.f, 0.f, 0.f, 0.f, 0.f, 0.f};
    int e = beg;
    for (; e + 16 <= end; e += 16) {
        int s0 = csr[e + q];
        int s1 = csr[e + 4 + q];
        int s2 = csr[e + 8 + q];
        int s3 = csr[e + 12 + q];
        float4 r0 = hp[(size_t)s0 * 16 + c];
        float4 r1 = hp[(size_t)s1 * 16 + c];
        float4 r2 = hp[(size_t)s2 * 16 + c];
        float4 r3 = hp[(size_t)s3 * 16 + c];
        const __half* h0 = (const __half*)&r0;
        const __half* h1 = (const __half*)&r1;
        const __half* h2 = (const __half*)&r2;
        const __half* h3 = (const __half*)&r3;
#pragma unroll
        for (int j = 0; j < 8; ++j) a[j] += __half2float(h0[j]);
#pragma unroll
        for (int j = 0; j < 8; ++j) a[j] += __half2float(h1[j]);
#pragma unroll
        for (int j = 0; j < 8; ++j) a[j] += __half2float(h2[j]);
#pragma unroll
        for (int j = 0; j < 8; ++j) a[j] += __half2float(h3[j]);
    }
    for (; e < end; e += 8) {
        const int last = end - 1;
        int i0 = e + q, i1 = e + 4 + q;
        float m0 = (i0 < end) ? 1.f : 0.f;
        float m1 = (i1 < end) ? 1.f : 0.f;
        int s0 = csr[min(i0, last)];
        int s1 = csr[min(i1, last)];
        float4 r0 = hp[(size_t)s0 * 16 + c];
        float4 r1 = hp[(size_t)s1 * 16 + c];
        const __half* h0 = (const __half*)&r0;
        const __half* h1 = (const __half*)&r1;
#pragma unroll
        for (int j = 0; j < 8; ++j) a[j] = fmaf(__half2float(h0[j]), m0, a[j]);
#pragma unroll
        for (int j = 0; j < 8; ++j) a[j] = fmaf(__half2float(h1[j]), m1, a[j]);
    }
#pragma unroll
    for (int j = 0; j < 8; ++j) {
        a[j] += __shfl_xor(a[j], 16);
        a[j] += __shfl_xor(a[j], 32);
    }
    {  // self-loop
        float4 rs = hp[(size_t)wid * 16 + c];
        const __half* hs = (const __half*)&rs;
#pragma unroll
        for (int j = 0; j < 8; ++j) a[j] += __half2float(hs[j]);
    }
    float4 b0 = ((const float4*)bias)[2 * c];
    float4 b1 = ((const float4*)bias)[2 * c + 1];
    float z[8];
    z[0] = fmaf(di, a[0], b0.x); z[1] = fmaf(di, a[1], b0.y);
    z[2] = fmaf(di, a[2], b0.z); z[3] = fmaf(di, a[3], b0.w);
    z[4] = fmaf(di, a[4], b1.x); z[5] = fmaf(di, a[5], b1.y);
    z[6] = fmaf(di, a[6], b1.z); z[7] = fmaf(di, a[7], b1.w);
    if (RELU) {
#pragma unroll
        for (int j = 0; j < 8; ++j) z[j] = fmaxf(z[j], 0.f);
    }
    if (q == 0) {
        __half2 o[4] = {__float22half2_rn(make_float2(z[0], z[1])),
                        __float22half2_rn(make_float2(z[2], z[3])),
                        __float22half2_rn(make_float2(z[4], z[5])),
                        __float22half2_rn(make_float2(z[6], z[7]))};
        ((float4*)out)[(size_t)wid * 16 + c] = *(float4*)o;
    }
}

// C=64 final agg: 8 lanes x 16B per edge; 16 edges/iter (2 gathers); fp32 output.
__global__ __launch_bounds__(256) void agg64(const __half* __restrict__ h,  // [N][64]
                                             const float* __restrict__ dinv,
                                             const int* __restrict__ offs,
                                             const int* __restrict__ csr,
                                             const float* __restrict__ bias,
                                             float* __restrict__ out, int N) {
    const int wid = (blockIdx.x * 256 + threadIdx.x) >> 6;
    if (wid >= N) return;
    const int l = threadIdx.x & 63;
    const int q = l >> 3;  // edge slot 0..7
    const int c = l & 7;   // 16B chunk
    const int beg = offs[wid], end = offs[wid + 1];
    const float di = dinv[wid];
    const float4* __restrict__ hp = (const float4*)h;  // row = 8 float4

    float a[8] = {0.f, 0.f, 0.f, 0.f, 0.f, 0.f, 0.f, 0.f};
    int e = beg;
    for (; e + 16 <= end; e += 16) {
        int s0 = csr[e + q];
        int s1 = csr[e + 8 + q];
        float4 r0 = hp[(size_t)s0 * 8 + c];
        float4 r1 = hp[(size_t)s1 * 8 + c];
        const __half* h0 = (const __half*)&r0;
        const __half* h1 = (const __half*)&r1;
#pragma unroll
        for (int j = 0; j < 8; ++j) a[j] += __half2float(h0[j]);
#pragma unroll
        for (int j = 0; j < 8; ++j) a[j] += __half2float(h1[j]);
    }
    for (; e < end; e += 8) {
        const int last = end - 1;
        int i0 = e + q;
        float m0 = (i0 < end) ? 1.f : 0.f;
        int s0 = csr[min(i0, last)];
        float4 r0 = hp[(size_t)s0 * 8 + c];
        const __half* h0 = (const __half*)&r0;
#pragma unroll
        for (int j = 0; j < 8; ++j) a[j] = fmaf(__half2float(h0[j]), m0, a[j]);
    }
#pragma unroll
    for (int j = 0; j < 8; ++j) {
        a[j] += __shfl_xor(a[j], 8);
        a[j] += __shfl_xor(a[j], 16);
        a[j] += __shfl_xor(a[j], 32);
    }
    {
        float4 rs = hp[(size_t)wid * 8 + c];
        const __half* hs = (const __half*)&rs;
#pragma unroll
        for (int j = 0; j < 8; ++j) a[j] += __half2float(hs[j]);
    }
    float4 b0 = ((const float4*)bias)[2 * c];
    float4 b1 = ((const float4*)bias)[2 * c + 1];
    float z[8];
    z[0] = fmaf(di, a[0], b0.x); z[1] = fmaf(di, a[1], b0.y);
    z[2] = fmaf(di, a[2], b0.z); z[3] = fmaf(di, a[3], b0.w);
    z[4] = fmaf(di, a[4], b1.x); z[5] = fmaf(di, a[5], b1.y);
    z[6] = fmaf(di, a[6], b1.z); z[7] = fmaf(di, a[7], b1.w);
    if (q == 0) {
        ((float4*)out)[(size_t)wid * 16 + 2 * c] = make_float4(z[0], z[1], z[2], z[3]);
        ((float4*)out)[(size_t)wid * 16 + 2 * c + 1] = make_float4(z[4], z[5], z[6], z[7]);
    }
}

// ---------------- launch ----------------

extern "C" void kernel_launch(void* const* d_in, const int* in_sizes, int n_in,
                              void* d_out, int out_size, void* d_ws, size_t ws_size,
                              hipStream_t stream) {
    const float* x  = (const float*)d_in[0];
    const int*   ei = (const int*)d_in[1];
    const float* W1 = (const float*)d_in[2];
    const float* b1 = (const float*)d_in[3];
    const float* W2 = (const float*)d_in[4];
    const float* b2 = (const float*)d_in[5];
    const float* W3 = (const float*)d_in[6];
    const float* b3 = (const float*)d_in[7];

    const int N = in_sizes[0] / 128;
    const int E = in_sizes[1] / 2;
    const int* row = ei;       // sources
    const int* col = ei + E;   // targets

    const int NB = (N + BMASK) >> BSH;       // 256-node buckets
    const int B1 = (E + CHUNK - 1) / CHUNK;
    const int NBB1 = NB * B1;

    char* p = (char*)d_ws;
    auto alloc = [&](size_t bytes) {
        char* r = p;
        p += (bytes + 255) & ~(size_t)255;
        return r;
    };
    int*    offs  = (int*)alloc((size_t)(N + 1) * 4);
    float*  dinv  = (float*)alloc((size_t)N * 4);
    int*    histG = (int*)alloc((size_t)NBB1 * 4);
    int*    bsum  = (int*)alloc(1024 * 4);
    int*    ebuf  = (int*)alloc((size_t)E * 4);
    int*    csr   = (int*)alloc((size_t)E * 4);
    __half* bufA  = (__half*)alloc((size_t)N * 128 * 2);
    __half* bufB  = (__half*)alloc((size_t)N * 128 * 2);
    __half* wT1   = (__half*)alloc(16384 * 2);
    __half* wT2   = (__half*)alloc(16384 * 2);
    __half* wT3   = (__half*)alloc(8192 * 2);

    const int nsb = (NBB1 + 1023) / 1024;

    // CSR build
    hist_pass<<<B1, 256, 0, stream>>>(col, E, NB, B1, histG);
    scan_blocks<<<nsb, 256, 0, stream>>>(histG, NBB1, bsum);
    scan_single<<<1, 256, 0, stream>>>(bsum, nsb);
    scatter_pass<<<B1, 256, 0, stream>>>(row, col, E, NB, B1, histG, bsum, ebuf);
    build_csr<<<NB, 256, 0, stream>>>(ebuf, histG, bsum, NB, B1, N, E, offs, dinv, csr);

    prep_wT<<<160, 256, 0, stream>>>(W1, W2, W3, wT1, wT2, wT3);

    const int gTile = (N + 127) / 128;
    const int gAgg = (N + 3) / 4;

    // layer 1 (fused fp32->fp16 cast in GEMM)
    gemm_x<<<gTile, 256, 0, stream>>>(x, wT1, dinv, bufA, N);
    agg128<true><<<gAgg, 256, 0, stream>>>(bufA, dinv, offs, csr, b1, bufB, N);

    // layer 2
    gemm_f16<128><<<gTile, 256, 0, stream>>>(bufB, wT2, dinv, bufA, N);
    agg128<true><<<gAgg, 256, 0, stream>>>(bufA, dinv, offs, csr, b2, bufB, N);

    // layer 3 (64 cols), final agg -> fp32 out
    gemm_f16<64><<<gTile, 256, 0, stream>>>(bufB, wT3, dinv, bufA, N);
    agg64<<<gAgg, 256, 0, stream>>>(bufA, dinv, offs, csr, b3, (float*)d_out, N);
}